// Round 11
// baseline (839.995 us; speedup 1.0000x reference)
//
#include <hip/hip_runtime.h>
#include <hip/hip_bf16.h>
#include <stdint.h>

typedef __attribute__((ext_vector_type(8))) short short8;
typedef __attribute__((ext_vector_type(4))) float f32x4;
typedef __hip_bfloat16 bf16;

#define MFMA16(a, b, c) __builtin_amdgcn_mfma_f32_16x16x32_bf16(a, b, c, 0, 0, 0)

__device__ __forceinline__ uint32_t swz(uint32_t row, uint32_t bir) {
  return bir ^ ((row & 7u) << 4);
}
__device__ __forceinline__ short f2bs(float v) {
  bf16 b = __float2bfloat16(v);
  return *reinterpret_cast<short*>(&b);
}
__device__ __forceinline__ float b2f(bf16 b) { return __bfloat162float(b); }

__device__ __forceinline__ short8 cvt8(f32x4 a, f32x4 b) {
  short8 v;
  v[0] = f2bs(a[0]); v[1] = f2bs(a[1]); v[2] = f2bs(a[2]); v[3] = f2bs(a[3]);
  v[4] = f2bs(b[0]); v[5] = f2bs(b[1]); v[6] = f2bs(b[2]); v[7] = f2bs(b[3]);
  return v;
}

// async global->LDS, 16B/lane; LDS dest = wave-uniform base + lane*16.
__device__ __forceinline__ void gl_lds16(const void* g, void* l) {
  __builtin_amdgcn_global_load_lds(
      (const __attribute__((address_space(1))) unsigned int*)g,
      (__attribute__((address_space(3))) unsigned int*)l, 16, 0, 0);
}

// ---------------------------------------------------------------------------
// conv_w: f32 weights -> SWIZZLED bf16 row-blobs (for gl_lds staging);
// biases -> linear bf16; rpe pre-gathered [8][49pad][64] (cols>=49 zero).
// ---------------------------------------------------------------------------
__global__ __launch_bounds__(256) void k_conv_w4(
    const float* __restrict__ wqkv, const float* __restrict__ bqkv,
    const float* __restrict__ wo,   const float* __restrict__ bo,
    const float* __restrict__ rpe,  const int* __restrict__ relidx,
    char* __restrict__ wqkvb, bf16* __restrict__ bqkvb,
    char* __restrict__ wob,   bf16* __restrict__ bob,
    bf16* __restrict__ rpew)
{
  int b = blockIdx.x, t = threadIdx.x;
  if (b < 384) {                       // wqkv: 1536x512 -> [1536][1024B] swz
    long i = (long)b * 2048 + t * 8;
    int row = (int)(i >> 9);
    uint32_t g = ((uint32_t)i & 511u) >> 3;
    f32x4 a = *(const f32x4*)(wqkv + i), c = *(const f32x4*)(wqkv + i + 4);
    *reinterpret_cast<short8*>(wqkvb + (size_t)row * 1024 + ((g * 16) ^ ((row & 7u) << 4))) = cvt8(a, c);
  } else if (b < 512) {                // wo: 512x512 -> [512][1024B] swz
    long i = (long)(b - 384) * 2048 + t * 8;
    int row = (int)(i >> 9);
    uint32_t g = ((uint32_t)i & 511u) >> 3;
    f32x4 a = *(const f32x4*)(wo + i), c = *(const f32x4*)(wo + i + 4);
    *reinterpret_cast<short8*>(wob + (size_t)row * 1024 + ((g * 16) ^ ((row & 7u) << 4))) = cvt8(a, c);
  } else if (b == 512) {
    for (int j = t; j < 1536; j += 256) bqkvb[j] = __float2bfloat16(bqkv[j]);
    for (int j = t; j < 512;  j += 256) bob[j]  = __float2bfloat16(bo[j]);
  } else {
    int h = b - 513;
    for (int e = t; e < 3136; e += 256) {
      int q = e >> 6, c = e & 63;
      float v = (c < 49) ? rpe[(long)relidx[q * 49 + c] * 8 + h] : 0.f;
      rpew[h * 3136 + e] = __float2bfloat16(v);
    }
  }
}

// ---------------------------------------------------------------------------
// conv_x: x f32 natural [127008][512] -> xb [127232 rows][1024B] pre-swizzled
// bf16, swizzle keyed by GLOBAL row (R&7). Rows >= 127008 zeroed.
// ---------------------------------------------------------------------------
__global__ __launch_bounds__(256) void k_conv_x3(
    const float* __restrict__ x, char* __restrict__ xb)
{
  int R  = blockIdx.x * 4 + (threadIdx.x >> 6);
  int c8 = threadIdx.x & 63;
  f32x4 a = {0.f, 0.f, 0.f, 0.f}, b = a;
  if (R < 127008) {
    a = *(const f32x4*)(x + (size_t)R * 512 + c8 * 8);
    b = *(const f32x4*)(x + (size_t)R * 512 + c8 * 8 + 4);
  }
  *reinterpret_cast<short8*>(xb + (size_t)R * 1024 + ((uint32_t)(c8 * 16) ^ ((R & 7u) << 4))) = cvt8(a, b);
}

// ---------------------------------------------------------------------------
// k_qkv_gemm5: per-batch chunk, natural-row M-tiles, 2-PHASE DOUBLE-BUFFER
// (stage k0+1 issued before MFMA(k0); one barrier/step). LDS 64 KB.
// grid 1536 = 125 mtiles x 12 nb XCD-grouped; block 256 / 4 waves.
// A-frag swizzle keyed by GLOBAL row (row0 odd-batch fix, round 10).
// ---------------------------------------------------------------------------
__global__ __launch_bounds__(256) void k_qkv_gemm5(
    const char* __restrict__ xb,      // [127232][1024B] swizzled (global-row key)
    const char* __restrict__ wqkvb,   // [1536][1024B] swizzled
    const bf16* __restrict__ bqkvb,   // [1536]
    char* __restrict__ blob,          // [3][324][8][8192B] chunk-local
    int cb_)                          // chunk batch 0..7
{
  __shared__ __align__(16) char sA[2][16384];
  __shared__ __align__(16) char sB[2][16384];

  const int tid = threadIdx.x, lane = tid & 63, w = tid >> 6;
  const int r16 = lane & 15, hi = lane >> 4;

  const int raw = blockIdx.x;
  const int xcd = raw & 7, grp = raw >> 3;
  const int nb = grp % 12, mg = grp / 12;
  const int mtile = mg * 8 + xcd;
  if (mtile >= 125) return;
  const int row0 = cb_ * 15876 + mtile * 128;

  const char* Abase = xb + (size_t)row0 * 1024;
  const char* Bbase = wqkvb + (size_t)nb * 131072;

  const uint32_t rxA = ((uint32_t)((r16 + row0) & 7)) << 4;
  const uint32_t rxB = ((uint32_t)(r16 & 7)) << 4;

  const int jrow = lane >> 3, jcol = (lane & 7) * 16;

  const f32x4 fz = {0.f, 0.f, 0.f, 0.f};
  f32x4 acc[4][4];
  #pragma unroll
  for (int m = 0; m < 4; ++m)
    #pragma unroll
    for (int n = 0; n < 4; ++n) acc[m][n] = fz;

  // prologue: stage slice 0 into buffer 0
  #pragma unroll
  for (int j = 0; j < 8; ++j) {
    int ch = w * 8 + j;
    if (ch < 16)
      gl_lds16(Abase + (size_t)(ch * 8 + jrow) * 1024 + jcol, sA[0] + ch * 1024);
    else
      gl_lds16(Bbase + (size_t)((ch - 16) * 8 + jrow) * 1024 + jcol, sB[0] + (ch - 16) * 1024);
  }
  __syncthreads();

  for (int k0 = 0; k0 < 8; ++k0) {
    const int cur = k0 & 1, nxt = cur ^ 1;
    if (k0 < 7) {  // issue next-slice loads; they fly during the MFMAs below
      #pragma unroll
      for (int j = 0; j < 8; ++j) {
        int ch = w * 8 + j;
        if (ch < 16)
          gl_lds16(Abase + (size_t)(ch * 8 + jrow) * 1024 + (k0 + 1) * 128 + jcol,
                   sA[nxt] + ch * 1024);
        else
          gl_lds16(Bbase + (size_t)((ch - 16) * 8 + jrow) * 1024 + (k0 + 1) * 128 + jcol,
                   sB[nxt] + (ch - 16) * 1024);
      }
    }
    #pragma unroll
    for (int ks = 0; ks < 2; ++ks) {
      uint32_t cb = (uint32_t)((ks * 4 + hi) * 16);
      short8 aF[4], bF[4];
      #pragma unroll
      for (int m = 0; m < 4; ++m)
        aF[m] = *(const short8*)(sA[cur] + ((w & 1) * 64 + m * 16 + r16) * 128 + (cb ^ rxA));
      #pragma unroll
      for (int n = 0; n < 4; ++n)
        bF[n] = *(const short8*)(sB[cur] + ((w >> 1) * 64 + n * 16 + r16) * 128 + (cb ^ rxB));
      #pragma unroll
      for (int m = 0; m < 4; ++m)
        #pragma unroll
        for (int n = 0; n < 4; ++n)
          acc[m][n] = MFMA16(aF[m], bF[n], acc[m][n]);
    }
    __syncthreads();  // drains vmcnt: next buffer ready; cur safe to overwrite
  }

  // epilogue: wave quadrant = rows (w&1)*64.., cols (w>>1)*64 of nb*128..
  const int gcol = nb * 128 + (w >> 1) * 64;   // 64-aligned
  const int t = gcol >> 9;                     // 0=q 1=k 2=v
  const int h = (gcol >> 6) & 7;
  const float scale = (t == 0) ? 0.125f : 1.0f;

  float bias4[4];
  #pragma unroll
  for (int n = 0; n < 4; ++n) bias4[n] = b2f(bqkvb[gcol + n * 16 + r16]);

  #pragma unroll
  for (int m = 0; m < 4; ++m)
    #pragma unroll
    for (int r = 0; r < 4; ++r) {
      int rnat = row0 + (w & 1) * 64 + m * 16 + hi * 4 + r;
      int rem = rnat - cb_ * 15876;
      if (rem >= 15876) continue;              // outside this chunk/batch
      int y = rem / 126, xc = rem - y * 126;
      int qi = y / 7, ph = y - qi * 7;
      int qj = xc / 7, pw = xc - qj * 7;
      int wiL = qi * 18 + qj, wrow = ph * 7 + pw;
      char* tile = blob + ((size_t)(t * 324 + wiL) * 8 + h) * 8192;
      #pragma unroll
      for (int n = 0; n < 4; ++n) {
        int d = n * 16 + r16;
        bf16 v = __float2bfloat16((acc[m][n][r] + bias4[n]) * scale);
        if (t < 2)
          *(bf16*)(tile + wrow * 128 + ((uint32_t)(2 * d) ^ ((wrow & 7u) << 4))) = v;
        else
          *(bf16*)(tile + wrow * 128 + 2 * d) = v;
      }
    }
}

// ---------------------------------------------------------------------------
// k_attn3: per (window, head) of chunk. Proven structure (round 10).
// ---------------------------------------------------------------------------
__global__ __launch_bounds__(256) void k_attn3(
    const char* __restrict__ blob,    // [3][324][8][8192B]
    const bf16* __restrict__ rpew,    // [8][49pad][64]
    char* __restrict__ attnb,         // [127104][1024B] swizzled natural rows
    int cb_)
{
  __shared__ __align__(16) char sQ[8192];
  __shared__ __align__(16) char sK[8192];
  __shared__ __align__(16) char sV[8192];
  __shared__ __align__(16) char sP[8192];

  const int tid = threadIdx.x, lane = tid & 63, w = tid >> 6;
  const int r16 = lane & 15, hi = lane >> 4;
  const int wiL = blockIdx.x >> 3, h = blockIdx.x & 7;

  const char* qb = blob + ((size_t)(0 * 324 + wiL) * 8 + h) * 8192;
  const char* kb = blob + ((size_t)(1 * 324 + wiL) * 8 + h) * 8192;
  const char* vb = blob + ((size_t)(2 * 324 + wiL) * 8 + h) * 8192;

  #pragma unroll
  for (int j = 0; j < 6; ++j) {
    int ch = w * 6 + j;
    int rg = ch >> 3, sub = ch & 7;
    const char* src = (rg == 0 ? qb : rg == 1 ? kb : vb) + sub * 1024 + lane * 16;
    char* dst = (rg == 0 ? sQ : rg == 1 ? sK : sV) + sub * 1024;
    gl_lds16(src, dst);
  }
  __syncthreads();

  const f32x4 fz = {0.f, 0.f, 0.f, 0.f};

  // S = q k^T (wave w owns q-rows w*16..)
  f32x4 s[4];
  #pragma unroll
  for (int n = 0; n < 4; ++n) s[n] = fz;
  #pragma unroll
  for (int k0 = 0; k0 < 2; ++k0) {
    int qrow = w * 16 + r16;
    short8 a = *(const short8*)(sQ + qrow * 128 + swz(qrow, k0 * 64 + hi * 16));
    #pragma unroll
    for (int n = 0; n < 4; ++n) {
      int krow = n * 16 + r16;
      short8 kf = *(const short8*)(sK + krow * 128 + swz(krow, k0 * 64 + hi * 16));
      s[n] = MFMA16(a, kf, s[n]);
    }
  }

  // +RPE, mask, in-register softmax
  #pragma unroll
  for (int n = 0; n < 4; ++n) {
    int col = n * 16 + r16;
    #pragma unroll
    for (int rr = 0; rr < 4; ++rr) {
      int qrow = w * 16 + hi * 4 + rr;
      int qc = qrow < 49 ? qrow : 48;
      float sv = s[n][rr] + b2f(rpew[h * 3136 + qc * 64 + col]);
      if (col >= 49) sv = -1e30f;
      s[n][rr] = sv;
    }
  }
  #pragma unroll
  for (int rr = 0; rr < 4; ++rr) {
    float mx = fmaxf(fmaxf(s[0][rr], s[1][rr]), fmaxf(s[2][rr], s[3][rr]));
    mx = fmaxf(mx, __shfl_xor(mx, 1));
    mx = fmaxf(mx, __shfl_xor(mx, 2));
    mx = fmaxf(mx, __shfl_xor(mx, 4));
    mx = fmaxf(mx, __shfl_xor(mx, 8));
    float su = 0.f;
    #pragma unroll
    for (int n = 0; n < 4; ++n) {
      float e = __expf(s[n][rr] - mx);
      s[n][rr] = e;
      su += e;
    }
    su += __shfl_xor(su, 1);
    su += __shfl_xor(su, 2);
    su += __shfl_xor(su, 4);
    su += __shfl_xor(su, 8);
    float inv = 1.f / su;
    #pragma unroll
    for (int n = 0; n < 4; ++n) s[n][rr] *= inv;
  }

  // P -> wave-private slab (A-frag layout)
  char* pw = sP + w * 2048;
  #pragma unroll
  for (int n = 0; n < 4; ++n)
    #pragma unroll
    for (int rr = 0; rr < 4; ++rr) {
      int rl = hi * 4 + rr, col = n * 16 + r16;
      *(bf16*)(pw + rl * 128 + swz(rl, 2 * col)) = __float2bfloat16(s[n][rr]);
    }
  __syncthreads();  // everyone done reading sQ/sK

  // cooperative transpose: sV (linear [tok][d]) -> sVt(=sQ) [d][tok] swizzled
  char* sVt = sQ;
  {
    int k = tid >> 2, c0 = (tid & 3) * 16;
    short8 v0 = *(const short8*)(sV + k * 128 + 2 * c0);
    short8 v1 = *(const short8*)(sV + k * 128 + 2 * c0 + 16);
    #pragma unroll
    for (int e = 0; e < 8; ++e) {
      int c = c0 + e;
      *(short*)(sVt + c * 128 + ((uint32_t)(2 * k) ^ ((c & 7u) << 4))) = v0[e];
      int c2 = c0 + 8 + e;
      *(short*)(sVt + c2 * 128 + ((uint32_t)(2 * k) ^ ((c2 & 7u) << 4))) = v1[e];
    }
  }
  __syncthreads();

  // O = P @ V
  f32x4 o[4];
  #pragma unroll
  for (int n = 0; n < 4; ++n) o[n] = fz;
  #pragma unroll
  for (int k0 = 0; k0 < 2; ++k0) {
    short8 a = *(const short8*)(pw + r16 * 128 + swz(r16, k0 * 64 + hi * 16));
    #pragma unroll
    for (int n = 0; n < 4; ++n) {
      int d = n * 16 + r16;
      short8 vf = *(const short8*)(sVt + d * 128 + swz(d, k0 * 64 + hi * 16));
      o[n] = MFMA16(a, vf, o[n]);
    }
  }

  // write O -> natural swizzled rows (only wrow < 49); key = global row &7
  const int qi = wiL / 18, qj = wiL - qi * 18;
  const int rowBase = cb_ * 15876 + qi * 882 + qj * 7;
  #pragma unroll
  for (int n = 0; n < 4; ++n) {
    int d = n * 16 + r16;
    #pragma unroll
    for (int r = 0; r < 4; ++r) {
      int wrow = w * 16 + hi * 4 + r;
      if (wrow < 49) {
        int rnat = rowBase + (wrow / 7) * 126 + wrow % 7;
        *(bf16*)(attnb + (size_t)rnat * 1024 +
                 ((uint32_t)(h * 128 + 2 * d) ^ ((rnat & 7u) << 4))) =
            __float2bfloat16(o[n][r]);
      }
    }
  }
}

// ---------------------------------------------------------------------------
// k_out_gemm5: 2-PHASE DOUBLE-BUFFER version of out-projection GEMM.
// grid 4000 = 993 mtiles x 4 nb XCD-grouped; block 256 / 4 waves; LDS 64 KB.
// row0 = mtile*128 is 8-aligned -> local swizzle key valid.
// ---------------------------------------------------------------------------
__global__ __launch_bounds__(256) void k_out_gemm5(
    const char* __restrict__ attnb,   // [127104][1024B] swizzled
    const char* __restrict__ wob,     // [512][1024B] swizzled
    const bf16* __restrict__ bob,     // [512]
    float* __restrict__ out)          // [127008][512] f32
{
  __shared__ __align__(16) char sA[2][16384];
  __shared__ __align__(16) char sB[2][16384];

  const int tid = threadIdx.x, lane = tid & 63, w = tid >> 6;
  const int r16 = lane & 15, hi = lane >> 4;

  const int raw = blockIdx.x;
  const int xcd = raw & 7, grp = raw >> 3;
  const int nb = grp & 3, mg = grp >> 2;
  const int mtile = mg * 8 + xcd;
  if (mtile >= 993) return;
  const int row0 = mtile * 128;

  const char* Abase = attnb + (size_t)row0 * 1024;
  const char* Bbase = wob + (size_t)nb * 131072;

  const int jrow = lane >> 3, jcol = (lane & 7) * 16;
  const uint32_t rx = ((uint32_t)(r16 & 7)) << 4;

  const f32x4 fz = {0.f, 0.f, 0.f, 0.f};
  f32x4 acc[4][4];
  #pragma unroll
  for (int m = 0; m < 4; ++m)
    #pragma unroll
    for (int n = 0; n < 4; ++n) acc[m][n] = fz;

  #pragma unroll
  for (int j = 0; j < 8; ++j) {
    int ch = w * 8 + j;
    if (ch < 16)
      gl_lds16(Abase + (size_t)(ch * 8 + jrow) * 1024 + jcol, sA[0] + ch * 1024);
    else
      gl_lds16(Bbase + (size_t)((ch - 16) * 8 + jrow) * 1024 + jcol, sB[0] + (ch - 16) * 1024);
  }
  __syncthreads();

  for (int k0 = 0; k0 < 8; ++k0) {
    const int cur = k0 & 1, nxt = cur ^ 1;
    if (k0 < 7) {
      #pragma unroll
      for (int j = 0; j < 8; ++j) {
        int ch = w * 8 + j;
        if (ch < 16)
          gl_lds16(Abase + (size_t)(ch * 8 + jrow) * 1024 + (k0 + 1) * 128 + jcol,
                   sA[nxt] + ch * 1024);
        else
          gl_lds16(Bbase + (size_t)((ch - 16) * 8 + jrow) * 1024 + (k0 + 1) * 128 + jcol,
                   sB[nxt] + (ch - 16) * 1024);
      }
    }
    #pragma unroll
    for (int ks = 0; ks < 2; ++ks) {
      uint32_t cb = (uint32_t)((ks * 4 + hi) * 16) ^ rx;
      short8 aF[4], bF[4];
      #pragma unroll
      for (int m = 0; m < 4; ++m)
        aF[m] = *(const short8*)(sA[cur] + ((w & 1) * 64 + m * 16 + r16) * 128 + cb);
      #pragma unroll
      for (int n = 0; n < 4; ++n)
        bF[n] = *(const short8*)(sB[cur] + ((w >> 1) * 64 + n * 16 + r16) * 128 + cb);
      #pragma unroll
      for (int m = 0; m < 4; ++m)
        #pragma unroll
        for (int n = 0; n < 4; ++n)
          acc[m][n] = MFMA16(aF[m], bF[n], acc[m][n]);
    }
    __syncthreads();
  }

  // epilogue: natural coalesced f32 stores
  #pragma unroll
  for (int n = 0; n < 4; ++n) {
    int col = nb * 128 + (w >> 1) * 64 + n * 16 + r16;
    float bias = b2f(bob[col]);
    #pragma unroll
    for (int m = 0; m < 4; ++m)
      #pragma unroll
      for (int r = 0; r < 4; ++r) {
        int row = row0 + (w & 1) * 64 + m * 16 + hi * 4 + r;
        if (row < 127008)
          out[(size_t)row * 512 + col] = acc[m][n][r] + bias;
      }
  }
}

extern "C" void kernel_launch(void* const* d_in, const int* in_sizes, int n_in,
                              void* d_out, int out_size, void* d_ws, size_t ws_size,
                              hipStream_t stream) {
  const float* x      = (const float*)d_in[0];
  const float* wqkv   = (const float*)d_in[1];
  const float* bqkv   = (const float*)d_in[2];
  const float* wo     = (const float*)d_in[3];
  const float* bo     = (const float*)d_in[4];
  const float* rpe    = (const float*)d_in[5];
  const int*   relidx = (const int*)d_in[6];

  char* ws = (char*)d_ws;
  const size_t OFF_XB    = 256;
  const size_t SZ_XB     = 127232ull * 1024;            // 130,285,568
  const size_t OFF_ATTNB = OFF_XB + SZ_XB;
  const size_t SZ_ATTNB  = 127104ull * 1024;            // 130,154,496
  const size_t OFF_BLOB  = OFF_ATTNB + SZ_ATTNB;
  const size_t SZ_BLOB   = 3ull * 324 * 8 * 8192;       // 63,700,992 (L3-resident)
  const size_t OFF_WQKV  = OFF_BLOB + SZ_BLOB;
  const size_t OFF_WO    = OFF_WQKV + 1536ull * 1024;
  const size_t OFF_BQKV  = OFF_WO + 512ull * 1024;
  const size_t OFF_BO    = OFF_BQKV + 3072;
  const size_t OFF_RPEW  = OFF_BO + 1024;               // total ~326.3 MB

  char* xb    = ws + OFF_XB;
  char* attnb = ws + OFF_ATTNB;
  char* blob  = ws + OFF_BLOB;
  char* wqkvb = ws + OFF_WQKV;
  char* wob   = ws + OFF_WO;
  bf16* bqkvb = (bf16*)(ws + OFF_BQKV);
  bf16* bob   = (bf16*)(ws + OFF_BO);
  bf16* rpew  = (bf16*)(ws + OFF_RPEW);

  k_conv_w4<<<dim3(521), dim3(256), 0, stream>>>(wqkv, bqkv, wo, bo, rpe, relidx,
                                                 wqkvb, bqkvb, wob, bob, rpew);
  k_conv_x3<<<dim3(31808), dim3(256), 0, stream>>>(x, xb);
  for (int b = 0; b < 8; ++b) {
    k_qkv_gemm5<<<dim3(1536), dim3(256), 0, stream>>>(xb, wqkvb, bqkvb, blob, b);
    k_attn3<<<dim3(2592), dim3(256), 0, stream>>>(blob, rpew, attnb, b);
  }
  k_out_gemm5<<<dim3(4000), dim3(256), 0, stream>>>(attnb, wob, bob, (float*)d_out);
}

// Round 12
// 703.496 us; speedup vs baseline: 1.1940x; 1.1940x over previous
//
#include <hip/hip_runtime.h>
#include <hip/hip_bf16.h>
#include <stdint.h>

typedef __attribute__((ext_vector_type(8))) short short8;
typedef __attribute__((ext_vector_type(4))) float f32x4;
typedef __hip_bfloat16 bf16;

#define MFMA16(a, b, c) __builtin_amdgcn_mfma_f32_16x16x32_bf16(a, b, c, 0, 0, 0)

__device__ __forceinline__ uint32_t swz(uint32_t row, uint32_t bir) {
  return bir ^ ((row & 7u) << 4);
}
__device__ __forceinline__ short f2bs(float v) {
  bf16 b = __float2bfloat16(v);
  return *reinterpret_cast<short*>(&b);
}
__device__ __forceinline__ float b2f(bf16 b) { return __bfloat162float(b); }

__device__ __forceinline__ short8 cvt8(f32x4 a, f32x4 b) {
  short8 v;
  v[0] = f2bs(a[0]); v[1] = f2bs(a[1]); v[2] = f2bs(a[2]); v[3] = f2bs(a[3]);
  v[4] = f2bs(b[0]); v[5] = f2bs(b[1]); v[6] = f2bs(b[2]); v[7] = f2bs(b[3]);
  return v;
}

// async global->LDS, 16B/lane; LDS dest = wave-uniform base + lane*16.
__device__ __forceinline__ void gl_lds16(const void* g, void* l) {
  __builtin_amdgcn_global_load_lds(
      (const __attribute__((address_space(1))) unsigned int*)g,
      (__attribute__((address_space(3))) unsigned int*)l, 16, 0, 0);
}

// ---------------------------------------------------------------------------
// conv_w: f32 weights -> SWIZZLED bf16 row-blobs (for gl_lds staging);
// biases -> linear bf16; rpe pre-gathered [8][49pad][64] (cols>=49 zero).
// ---------------------------------------------------------------------------
__global__ __launch_bounds__(256) void k_conv_w4(
    const float* __restrict__ wqkv, const float* __restrict__ bqkv,
    const float* __restrict__ wo,   const float* __restrict__ bo,
    const float* __restrict__ rpe,  const int* __restrict__ relidx,
    char* __restrict__ wqkvb, bf16* __restrict__ bqkvb,
    char* __restrict__ wob,   bf16* __restrict__ bob,
    bf16* __restrict__ rpew)
{
  int b = blockIdx.x, t = threadIdx.x;
  if (b < 384) {                       // wqkv: 1536x512 -> [1536][1024B] swz
    long i = (long)b * 2048 + t * 8;
    int row = (int)(i >> 9);
    uint32_t g = ((uint32_t)i & 511u) >> 3;
    f32x4 a = *(const f32x4*)(wqkv + i), c = *(const f32x4*)(wqkv + i + 4);
    *reinterpret_cast<short8*>(wqkvb + (size_t)row * 1024 + ((g * 16) ^ ((row & 7u) << 4))) = cvt8(a, c);
  } else if (b < 512) {                // wo: 512x512 -> [512][1024B] swz
    long i = (long)(b - 384) * 2048 + t * 8;
    int row = (int)(i >> 9);
    uint32_t g = ((uint32_t)i & 511u) >> 3;
    f32x4 a = *(const f32x4*)(wo + i), c = *(const f32x4*)(wo + i + 4);
    *reinterpret_cast<short8*>(wob + (size_t)row * 1024 + ((g * 16) ^ ((row & 7u) << 4))) = cvt8(a, c);
  } else if (b == 512) {
    for (int j = t; j < 1536; j += 256) bqkvb[j] = __float2bfloat16(bqkv[j]);
    for (int j = t; j < 512;  j += 256) bob[j]  = __float2bfloat16(bo[j]);
  } else {
    int h = b - 513;
    for (int e = t; e < 3136; e += 256) {
      int q = e >> 6, c = e & 63;
      float v = (c < 49) ? rpe[(long)relidx[q * 49 + c] * 8 + h] : 0.f;
      rpew[h * 3136 + e] = __float2bfloat16(v);
    }
  }
}

// ---------------------------------------------------------------------------
// conv_x: x f32 natural [127008][512] -> xb [127232 rows][1024B] pre-swizzled
// bf16, swizzle keyed by GLOBAL row (R&7). Rows >= 127008 zeroed.
// ---------------------------------------------------------------------------
__global__ __launch_bounds__(256) void k_conv_x3(
    const float* __restrict__ x, char* __restrict__ xb)
{
  int R  = blockIdx.x * 4 + (threadIdx.x >> 6);
  int c8 = threadIdx.x & 63;
  f32x4 a = {0.f, 0.f, 0.f, 0.f}, b = a;
  if (R < 127008) {
    a = *(const f32x4*)(x + (size_t)R * 512 + c8 * 8);
    b = *(const f32x4*)(x + (size_t)R * 512 + c8 * 8 + 4);
  }
  *reinterpret_cast<short8*>(xb + (size_t)R * 1024 + ((uint32_t)(c8 * 16) ^ ((R & 7u) << 4))) = cvt8(a, b);
}

// ---------------------------------------------------------------------------
// k_qkv_gemm6: per 2-BATCH chunk (31752 rows), natural-row M-tiles,
// single-buffer 2-barrier structure (round-10 proven; dbuf regressed r11).
// grid 3072 = 249 mtiles x 12 nb XCD-grouped; block 256 / 4 waves; LDS 32KB.
// A-frag swizzle keyed by GLOBAL row (round-10 fix; row0 is 8-aligned here).
// ---------------------------------------------------------------------------
__global__ __launch_bounds__(256) void k_qkv_gemm6(
    const char* __restrict__ xb,      // [127232][1024B] swizzled (global-row key)
    const char* __restrict__ wqkvb,   // [1536][1024B] swizzled
    const bf16* __restrict__ bqkvb,   // [1536]
    char* __restrict__ blob,          // [3][648][8][8192B] chunk-local
    int cb_)                          // chunk 0..3 (2 batches each)
{
  __shared__ __align__(16) char sA[16384];
  __shared__ __align__(16) char sB[16384];

  const int tid = threadIdx.x, lane = tid & 63, w = tid >> 6;
  const int r16 = lane & 15, hi = lane >> 4;

  const int raw = blockIdx.x;
  const int xcd = raw & 7, grp = raw >> 3;
  const int nb = grp % 12, mg = grp / 12;
  const int mtile = mg * 8 + xcd;
  if (mtile >= 249) return;
  const int row0 = cb_ * 31752 + mtile * 128;

  const char* Abase = xb + (size_t)row0 * 1024;
  const char* Bbase = wqkvb + (size_t)nb * 131072;

  const uint32_t rxA = ((uint32_t)((r16 + row0) & 7)) << 4;
  const uint32_t rxB = ((uint32_t)(r16 & 7)) << 4;

  const f32x4 fz = {0.f, 0.f, 0.f, 0.f};
  f32x4 acc[4][4];
  #pragma unroll
  for (int m = 0; m < 4; ++m)
    #pragma unroll
    for (int n = 0; n < 4; ++n) acc[m][n] = fz;

  for (int k0 = 0; k0 < 8; ++k0) {
    if (k0) __syncthreads();
    #pragma unroll
    for (int j = 0; j < 8; ++j) {
      int ch = w * 8 + j;
      if (ch < 16)
        gl_lds16(Abase + (size_t)(ch * 8 + (lane >> 3)) * 1024 + k0 * 128 + (lane & 7) * 16,
                 sA + ch * 1024);
      else {
        int c2 = ch - 16;
        gl_lds16(Bbase + (size_t)(c2 * 8 + (lane >> 3)) * 1024 + k0 * 128 + (lane & 7) * 16,
                 sB + c2 * 1024);
      }
    }
    __syncthreads();

    #pragma unroll
    for (int ks = 0; ks < 2; ++ks) {
      uint32_t cb = (uint32_t)((ks * 4 + hi) * 16);
      short8 aF[4], bF[4];
      #pragma unroll
      for (int m = 0; m < 4; ++m)
        aF[m] = *(const short8*)(sA + ((w & 1) * 64 + m * 16 + r16) * 128 + (cb ^ rxA));
      #pragma unroll
      for (int n = 0; n < 4; ++n)
        bF[n] = *(const short8*)(sB + ((w >> 1) * 64 + n * 16 + r16) * 128 + (cb ^ rxB));
      #pragma unroll
      for (int m = 0; m < 4; ++m)
        #pragma unroll
        for (int n = 0; n < 4; ++n)
          acc[m][n] = MFMA16(aF[m], bF[n], acc[m][n]);
    }
  }

  // epilogue: wave quadrant = rows (w&1)*64.., cols (w>>1)*64 of nb*128..
  const int gcol = nb * 128 + (w >> 1) * 64;   // 64-aligned
  const int t = gcol >> 9;                     // 0=q 1=k 2=v
  const int h = (gcol >> 6) & 7;
  const float scale = (t == 0) ? 0.125f : 1.0f;

  float bias4[4];
  #pragma unroll
  for (int n = 0; n < 4; ++n) bias4[n] = b2f(bqkvb[gcol + n * 16 + r16]);

  #pragma unroll
  for (int m = 0; m < 4; ++m)
    #pragma unroll
    for (int r = 0; r < 4; ++r) {
      int rnat = row0 + (w & 1) * 64 + m * 16 + hi * 4 + r;
      int rem = rnat - cb_ * 31752;
      if (rem >= 31752) continue;              // outside this chunk
      int b2 = rem / 15876, rem2 = rem - b2 * 15876;
      int y = rem2 / 126, xc = rem2 - y * 126;
      int qi = y / 7, ph = y - qi * 7;
      int qj = xc / 7, pw = xc - qj * 7;
      int wiL = b2 * 324 + qi * 18 + qj, wrow = ph * 7 + pw;
      char* tile = blob + ((size_t)(t * 648 + wiL) * 8 + h) * 8192;
      #pragma unroll
      for (int n = 0; n < 4; ++n) {
        int d = n * 16 + r16;
        bf16 v = __float2bfloat16((acc[m][n][r] + bias4[n]) * scale);
        if (t < 2)
          *(bf16*)(tile + wrow * 128 + ((uint32_t)(2 * d) ^ ((wrow & 7u) << 4))) = v;
        else
          *(bf16*)(tile + wrow * 128 + 2 * d) = v;
      }
    }
}

// ---------------------------------------------------------------------------
// k_attn6: per (window, head) of 2-batch chunk (grid 5184). Round-10 proven
// structure; output to natural-layout swizzled rows (wrow<49 only).
// ---------------------------------------------------------------------------
__global__ __launch_bounds__(256) void k_attn6(
    const char* __restrict__ blob,    // [3][648][8][8192B]
    const bf16* __restrict__ rpew,    // [8][49pad][64]
    char* __restrict__ attnb,         // [127104][1024B] swizzled natural rows
    int cb_)
{
  __shared__ __align__(16) char sQ[8192];
  __shared__ __align__(16) char sK[8192];
  __shared__ __align__(16) char sV[8192];
  __shared__ __align__(16) char sP[8192];

  const int tid = threadIdx.x, lane = tid & 63, w = tid >> 6;
  const int r16 = lane & 15, hi = lane >> 4;
  const int wiL = blockIdx.x >> 3, h = blockIdx.x & 7;

  const char* qb = blob + ((size_t)(0 * 648 + wiL) * 8 + h) * 8192;
  const char* kb = blob + ((size_t)(1 * 648 + wiL) * 8 + h) * 8192;
  const char* vb = blob + ((size_t)(2 * 648 + wiL) * 8 + h) * 8192;

  #pragma unroll
  for (int j = 0; j < 6; ++j) {
    int ch = w * 6 + j;
    int rg = ch >> 3, sub = ch & 7;
    const char* src = (rg == 0 ? qb : rg == 1 ? kb : vb) + sub * 1024 + lane * 16;
    char* dst = (rg == 0 ? sQ : rg == 1 ? sK : sV) + sub * 1024;
    gl_lds16(src, dst);
  }
  __syncthreads();

  const f32x4 fz = {0.f, 0.f, 0.f, 0.f};

  // S = q k^T (wave w owns q-rows w*16..)
  f32x4 s[4];
  #pragma unroll
  for (int n = 0; n < 4; ++n) s[n] = fz;
  #pragma unroll
  for (int k0 = 0; k0 < 2; ++k0) {
    int qrow = w * 16 + r16;
    short8 a = *(const short8*)(sQ + qrow * 128 + swz(qrow, k0 * 64 + hi * 16));
    #pragma unroll
    for (int n = 0; n < 4; ++n) {
      int krow = n * 16 + r16;
      short8 kf = *(const short8*)(sK + krow * 128 + swz(krow, k0 * 64 + hi * 16));
      s[n] = MFMA16(a, kf, s[n]);
    }
  }

  // +RPE, mask, in-register softmax
  #pragma unroll
  for (int n = 0; n < 4; ++n) {
    int col = n * 16 + r16;
    #pragma unroll
    for (int rr = 0; rr < 4; ++rr) {
      int qrow = w * 16 + hi * 4 + rr;
      int qc = qrow < 49 ? qrow : 48;
      float sv = s[n][rr] + b2f(rpew[h * 3136 + qc * 64 + col]);
      if (col >= 49) sv = -1e30f;
      s[n][rr] = sv;
    }
  }
  #pragma unroll
  for (int rr = 0; rr < 4; ++rr) {
    float mx = fmaxf(fmaxf(s[0][rr], s[1][rr]), fmaxf(s[2][rr], s[3][rr]));
    mx = fmaxf(mx, __shfl_xor(mx, 1));
    mx = fmaxf(mx, __shfl_xor(mx, 2));
    mx = fmaxf(mx, __shfl_xor(mx, 4));
    mx = fmaxf(mx, __shfl_xor(mx, 8));
    float su = 0.f;
    #pragma unroll
    for (int n = 0; n < 4; ++n) {
      float e = __expf(s[n][rr] - mx);
      s[n][rr] = e;
      su += e;
    }
    su += __shfl_xor(su, 1);
    su += __shfl_xor(su, 2);
    su += __shfl_xor(su, 4);
    su += __shfl_xor(su, 8);
    float inv = 1.f / su;
    #pragma unroll
    for (int n = 0; n < 4; ++n) s[n][rr] *= inv;
  }

  // P -> wave-private slab (A-frag layout)
  char* pw = sP + w * 2048;
  #pragma unroll
  for (int n = 0; n < 4; ++n)
    #pragma unroll
    for (int rr = 0; rr < 4; ++rr) {
      int rl = hi * 4 + rr, col = n * 16 + r16;
      *(bf16*)(pw + rl * 128 + swz(rl, 2 * col)) = __float2bfloat16(s[n][rr]);
    }
  __syncthreads();  // everyone done reading sQ/sK

  // cooperative transpose: sV (linear [tok][d]) -> sVt(=sQ) [d][tok] swizzled
  char* sVt = sQ;
  {
    int k = tid >> 2, c0 = (tid & 3) * 16;
    short8 v0 = *(const short8*)(sV + k * 128 + 2 * c0);
    short8 v1 = *(const short8*)(sV + k * 128 + 2 * c0 + 16);
    #pragma unroll
    for (int e = 0; e < 8; ++e) {
      int c = c0 + e;
      *(short*)(sVt + c * 128 + ((uint32_t)(2 * k) ^ ((c & 7u) << 4))) = v0[e];
      int c2 = c0 + 8 + e;
      *(short*)(sVt + c2 * 128 + ((uint32_t)(2 * k) ^ ((c2 & 7u) << 4))) = v1[e];
    }
  }
  __syncthreads();

  // O = P @ V
  f32x4 o[4];
  #pragma unroll
  for (int n = 0; n < 4; ++n) o[n] = fz;
  #pragma unroll
  for (int k0 = 0; k0 < 2; ++k0) {
    short8 a = *(const short8*)(pw + r16 * 128 + swz(r16, k0 * 64 + hi * 16));
    #pragma unroll
    for (int n = 0; n < 4; ++n) {
      int d = n * 16 + r16;
      short8 vf = *(const short8*)(sVt + d * 128 + swz(d, k0 * 64 + hi * 16));
      o[n] = MFMA16(a, vf, o[n]);
    }
  }

  // write O -> natural swizzled rows (only wrow < 49); key = global row &7
  const int b2 = wiL / 324, wr = wiL - b2 * 324;
  const int qi = wr / 18, qj = wr - qi * 18;
  const int rowBase = (cb_ * 2 + b2) * 15876 + qi * 882 + qj * 7;
  #pragma unroll
  for (int n = 0; n < 4; ++n) {
    int d = n * 16 + r16;
    #pragma unroll
    for (int r = 0; r < 4; ++r) {
      int wrow = w * 16 + hi * 4 + r;
      if (wrow < 49) {
        int rnat = rowBase + (wrow / 7) * 126 + wrow % 7;
        *(bf16*)(attnb + (size_t)rnat * 1024 +
                 ((uint32_t)(h * 128 + 2 * d) ^ ((rnat & 7u) << 4))) =
            __float2bfloat16(o[n][r]);
      }
    }
  }
}

// ---------------------------------------------------------------------------
// k_out_gemm3 (round-10 verbatim, 148 us proven): out = attn @ wo^T + bo.
// grid 4000 = 993 mtiles x 4 nb XCD-grouped; block 256 / 4 waves; LDS 32KB.
// ---------------------------------------------------------------------------
__global__ __launch_bounds__(256) void k_out_gemm3(
    const char* __restrict__ attnb,   // [127104][1024B] swizzled
    const char* __restrict__ wob,     // [512][1024B] swizzled
    const bf16* __restrict__ bob,     // [512]
    float* __restrict__ out)          // [127008][512] f32
{
  __shared__ __align__(16) char sA[16384];
  __shared__ __align__(16) char sB[16384];

  const int tid = threadIdx.x, lane = tid & 63, w = tid >> 6;
  const int r16 = lane & 15, hi = lane >> 4;

  const int raw = blockIdx.x;
  const int xcd = raw & 7, grp = raw >> 3;
  const int nb = grp & 3, mg = grp >> 2;
  const int mtile = mg * 8 + xcd;
  if (mtile >= 993) return;
  const int row0 = mtile * 128;

  const char* Abase = attnb + (size_t)row0 * 1024;
  const char* Bbase = wob + (size_t)nb * 131072;

  const f32x4 fz = {0.f, 0.f, 0.f, 0.f};
  f32x4 acc[4][4];
  #pragma unroll
  for (int m = 0; m < 4; ++m)
    #pragma unroll
    for (int n = 0; n < 4; ++n) acc[m][n] = fz;

  for (int k0 = 0; k0 < 8; ++k0) {
    if (k0) __syncthreads();
    #pragma unroll
    for (int j = 0; j < 8; ++j) {
      int ch = w * 8 + j;
      if (ch < 16)
        gl_lds16(Abase + (size_t)(ch * 8 + (lane >> 3)) * 1024 + k0 * 128 + (lane & 7) * 16,
                 sA + ch * 1024);
      else {
        int c2 = ch - 16;
        gl_lds16(Bbase + (size_t)(c2 * 8 + (lane >> 3)) * 1024 + k0 * 128 + (lane & 7) * 16,
                 sB + c2 * 1024);
      }
    }
    __syncthreads();

    #pragma unroll
    for (int ks = 0; ks < 2; ++ks) {
      uint32_t cb = (uint32_t)((ks * 4 + hi) * 16) ^ ((r16 & 7u) << 4);
      short8 aF[4], bF[4];
      #pragma unroll
      for (int m = 0; m < 4; ++m)
        aF[m] = *(const short8*)(sA + ((w & 1) * 64 + m * 16 + r16) * 128 + cb);
      #pragma unroll
      for (int n = 0; n < 4; ++n)
        bF[n] = *(const short8*)(sB + ((w >> 1) * 64 + n * 16 + r16) * 128 + cb);
      #pragma unroll
      for (int m = 0; m < 4; ++m)
        #pragma unroll
        for (int n = 0; n < 4; ++n)
          acc[m][n] = MFMA16(aF[m], bF[n], acc[m][n]);
    }
  }

  // epilogue: natural coalesced f32 stores
  #pragma unroll
  for (int n = 0; n < 4; ++n) {
    int col = nb * 128 + (w >> 1) * 64 + n * 16 + r16;
    float bias = b2f(bob[col]);
    #pragma unroll
    for (int m = 0; m < 4; ++m)
      #pragma unroll
      for (int r = 0; r < 4; ++r) {
        int row = row0 + (w & 1) * 64 + m * 16 + hi * 4 + r;
        if (row < 127008)
          out[(size_t)row * 512 + col] = acc[m][n][r] + bias;
      }
  }
}

extern "C" void kernel_launch(void* const* d_in, const int* in_sizes, int n_in,
                              void* d_out, int out_size, void* d_ws, size_t ws_size,
                              hipStream_t stream) {
  const float* x      = (const float*)d_in[0];
  const float* wqkv   = (const float*)d_in[1];
  const float* bqkv   = (const float*)d_in[2];
  const float* wo     = (const float*)d_in[3];
  const float* bo     = (const float*)d_in[4];
  const float* rpe    = (const float*)d_in[5];
  const int*   relidx = (const int*)d_in[6];

  char* ws = (char*)d_ws;
  const size_t OFF_XB    = 256;
  const size_t SZ_XB     = 127232ull * 1024;            // 130,285,568
  const size_t OFF_ATTNB = OFF_XB + SZ_XB;
  const size_t SZ_ATTNB  = 127104ull * 1024;            // 130,154,496
  const size_t OFF_BLOB  = OFF_ATTNB + SZ_ATTNB;
  const size_t SZ_BLOB   = 3ull * 648 * 8 * 8192;       // 127,401,984 (L3-fit)
  const size_t OFF_WQKV  = OFF_BLOB + SZ_BLOB;
  const size_t OFF_WO    = OFF_WQKV + 1536ull * 1024;
  const size_t OFF_BQKV  = OFF_WO + 512ull * 1024;
  const size_t OFF_BO    = OFF_BQKV + 3072;
  const size_t OFF_RPEW  = OFF_BO + 1024;               // total ~390 MB

  char* xb    = ws + OFF_XB;
  char* attnb = ws + OFF_ATTNB;
  char* blob  = ws + OFF_BLOB;
  char* wqkvb = ws + OFF_WQKV;
  char* wob   = ws + OFF_WO;
  bf16* bqkvb = (bf16*)(ws + OFF_BQKV);
  bf16* bob   = (bf16*)(ws + OFF_BO);
  bf16* rpew  = (bf16*)(ws + OFF_RPEW);

  k_conv_w4<<<dim3(521), dim3(256), 0, stream>>>(wqkv, bqkv, wo, bo, rpe, relidx,
                                                 wqkvb, bqkvb, wob, bob, rpew);
  k_conv_x3<<<dim3(31808), dim3(256), 0, stream>>>(x, xb);
  for (int c = 0; c < 4; ++c) {
    k_qkv_gemm6<<<dim3(3072), dim3(256), 0, stream>>>(xb, wqkvb, bqkvb, blob, c);
    k_attn6<<<dim3(5184), dim3(256), 0, stream>>>(blob, rpew, attnb, c);
  }
  k_out_gemm3<<<dim3(4000), dim3(256), 0, stream>>>(attnb, wob, bob, (float*)d_out);
}